// Round 6
// baseline (69.169 us; speedup 1.0000x reference)
//
#include <hip/hip_runtime.h>

// Problem constants (from reference): B=8192, N=34, D=16
#define BB 8192
#define NN 34
#define DD 16
#define PP 594        // #pairs: i in [0,32], j in [i,33]
#define XF 544        // NN*DD floats per batch

typedef float f32x4 __attribute__((ext_vector_type(4)));

// Compile-time pair table: p -> {i, j}
struct PairTab { uchar2 v[PP]; };
constexpr PairTab make_tab() {
    PairTab t{};
    int p = 0;
    for (int i = 0; i < NN - 1; ++i)
        for (int j = i; j < NN; ++j) {
            t.v[p].x = (unsigned char)i;
            t.v[p].y = (unsigned char)j;
            ++p;
        }
    return t;
}
__device__ __constant__ PairTab c_tab = make_tab();

// Wave partitions of pair-space by i (row lengths 34-i are triangular):
//  w0: i [0,5)   -> p [0,160)    160 pairs, 5 proj rows
//  w1: i [5,11)  -> p [160,319)  159 pairs, 6 proj rows
//  w2: i [11,18) -> p [319,459)  140 pairs, 7 proj rows
//  w3: i [18,33) -> p [459,594)  135 pairs, 15 proj rows
// Each wave needs proj only for its own i-range and x[j] for j>=i_start,
// so with a full private-staged x there is NO cross-wave dependency.

__global__ __launch_bounds__(256)
void BiInteraction_38577396253196_kernel(const float* __restrict__ x,
                                         const float* __restrict__ W,
                                         float* __restrict__ out)
{
    __shared__ float xs[XF];        // x[b]   (written redundantly by all waves)
    __shared__ float ws[DD * DD];   // W      (written redundantly by all waves)
    __shared__ float ps[NN * DD];   // proj[b] (each wave writes only its rows)

    const int t = threadIdx.x;
    const int w = t >> 6, lane = t & 63;
    const int b = blockIdx.x;

    // Per-wave partition constants (wave-uniform -> scalar branches).
    int istart, iend, pstart, pend;
    if (w == 0)      { istart = 0;  iend = 5;  pstart = 0;   pend = 160; }
    else if (w == 1) { istart = 5;  iend = 11; pstart = 160; pend = 319; }
    else if (w == 2) { istart = 11; iend = 18; pstart = 319; pend = 459; }
    else             { istart = 18; iend = 33; pstart = 459; pend = 594; }

    // Stage full x[b] (136 float4) and W (64 float4) — every wave writes the
    // whole thing: benign race (identical values), removes all barriers.
    // Redundant global reads hit L1 (same CU, same addresses).
    const f32x4* xg = (const f32x4*)(x + (size_t)b * XF);
    f32x4* xsv = (f32x4*)xs;
    xsv[lane]      = xg[lane];
    xsv[lane + 64] = xg[lane + 64];
    if (lane < 8) xsv[lane + 128] = xg[lane + 128];
    ((f32x4*)ws)[lane] = ((const f32x4*)W)[lane];

    __builtin_amdgcn_wave_barrier();   // pin LDS write -> read ordering in-wave

    // proj[n][e] = sum_d x[n][d] * W[d][e] for this wave's rows only.
    const int nq = (iend - istart) * DD;
    for (int q = lane; q < nq; q += 64) {
        const int n = istart + (q >> 4), e = q & 15;
        float acc = 0.f;
#pragma unroll
        for (int d = 0; d < DD; ++d)
            acc = fmaf(xs[n * DD + d], ws[d * DD + e], acc);
        ps[n * DD + e] = acc;
    }

    __builtin_amdgcn_wave_barrier();

    // Store this wave's contiguous p-chunk: flat float4 index g strided by
    // lane -> coalesced 1 KiB/wave stores.
    f32x4* og = (f32x4*)(out + (size_t)b * (PP * DD));
    const f32x4* psv = (const f32x4*)ps;
    const int n4 = (pend - pstart) * 4;
#pragma unroll 4
    for (int k = lane; k < n4; k += 64) {
        const int g = pstart * 4 + k;
        const int p = g >> 2, d4 = g & 3;
        const uchar2 pr = c_tab.v[p];
        og[g] = psv[pr.x * 4 + d4] * xsv[pr.y * 4 + d4];
    }
}

extern "C" void kernel_launch(void* const* d_in, const int* in_sizes, int n_in,
                              void* d_out, int out_size, void* d_ws, size_t ws_size,
                              hipStream_t stream) {
    const float* x = (const float*)d_in[0];   // [B, N, D] fp32
    const float* W = (const float*)d_in[1];   // [D, D] fp32
    float* out = (float*)d_out;               // [B, P*D] fp32

    BiInteraction_38577396253196_kernel<<<BB, 256, 0, stream>>>(x, W, out);
}

// Round 7
// 62.758 us; speedup vs baseline: 1.1022x; 1.1022x over previous
//
#include <hip/hip_runtime.h>

// Problem constants (from reference): B=8192, N=34, D=16
#define BB 8192
#define NN 34
#define DD 16
#define PP 594        // #pairs: i in [0,32], j in [i,33]
#define XF 544        // NN*DD floats per batch

typedef float f32x4 __attribute__((ext_vector_type(4)));

// Compile-time pair table: p -> {i, j}
struct PairTab { uchar2 v[PP]; };
constexpr PairTab make_tab() {
    PairTab t{};
    int p = 0;
    for (int i = 0; i < NN - 1; ++i)
        for (int j = i; j < NN; ++j) {
            t.v[p].x = (unsigned char)i;
            t.v[p].y = (unsigned char)j;
            ++p;
        }
    return t;
}
__device__ __constant__ PairTab c_tab = make_tab();

__device__ __forceinline__ void compute_proj(const float* __restrict__ xs,
                                             const float* __restrict__ ws,
                                             float* __restrict__ ps, int t)
{
    // 544 outputs = 2*256 + 32, 16 FMAs each
#pragma unroll
    for (int it = 0; it < 2; ++it) {
        const int q = t + it * 256;
        const int n = q >> 4, e = q & 15;
        float acc = 0.f;
#pragma unroll
        for (int d = 0; d < DD; ++d)
            acc = fmaf(xs[n * DD + d], ws[d * DD + e], acc);
        ps[q] = acc;
    }
    if (t < 32) {
        const int q = t + 512;
        const int n = q >> 4, e = q & 15;
        float acc = 0.f;
#pragma unroll
        for (int d = 0; d < DD; ++d)
            acc = fmaf(xs[n * DD + d], ws[d * DD + e], acc);
        ps[q] = acc;
    }
}

__device__ __forceinline__ void store_batch(float* __restrict__ outb,
                                            const float* __restrict__ ps,
                                            const float* __restrict__ xs, int t)
{
    // Flat float4 index strided by thread -> coalesced 1 KiB/wave stores.
    // 2376 = 9*256 + 72.
    f32x4* og = (f32x4*)outb;
    const f32x4* psv = (const f32x4*)ps;
    const f32x4* xsv = (const f32x4*)xs;
#pragma unroll
    for (int it = 0; it < 9; ++it) {
        const int k4 = t + it * 256;
        const int p = k4 >> 2, d4 = k4 & 3;
        const uchar2 pr = c_tab.v[p];
        og[k4] = psv[pr.x * 4 + d4] * xsv[pr.y * 4 + d4];
    }
    if (t < 72) {
        const int k4 = t + 9 * 256;
        const int p = k4 >> 2, d4 = k4 & 3;
        const uchar2 pr = c_tab.v[p];
        og[k4] = psv[pr.x * 4 + d4] * xsv[pr.y * 4 + d4];
    }
}

__global__ __launch_bounds__(256)
void BiInteraction_38577396253196_kernel(const float* __restrict__ x,
                                         const float* __restrict__ W,
                                         float* __restrict__ out)
{
    __shared__ float xs[2][XF];     // x for 2 consecutive batches
    __shared__ float ps[2][XF];     // proj for 2 batches
    __shared__ float ws[DD * DD];   // W

    const int t = threadIdx.x;
    const size_t b0 = (size_t)blockIdx.x * 2;

    // Stage BOTH batches up-front (one load burst: 272 contiguous float4)
    // plus W. One exposed HBM latency per two batches.
    const f32x4* xg = (const f32x4*)(x + b0 * XF);
    f32x4* xsv = (f32x4*)&xs[0][0];
    xsv[t] = xg[t];
    if (t < 16) xsv[t + 256] = xg[t + 256];
    if (t >= 192) ((f32x4*)ws)[t - 192] = ((const f32x4*)W)[t - 192];
    __syncthreads();

    // proj0
    compute_proj(&xs[0][0], ws, &ps[0][0], t);
    __syncthreads();

    // store batch0 (no readers -> stores stay in flight) overlapped with
    // compute of proj1 on the VALU.
    store_batch(out + b0 * (size_t)(PP * DD), &ps[0][0], &xs[0][0], t);
    compute_proj(&xs[1][0], ws, &ps[1][0], t);
    __syncthreads();

    // store batch1
    store_batch(out + (b0 + 1) * (size_t)(PP * DD), &ps[1][0], &xs[1][0], t);
}

extern "C" void kernel_launch(void* const* d_in, const int* in_sizes, int n_in,
                              void* d_out, int out_size, void* d_ws, size_t ws_size,
                              hipStream_t stream) {
    const float* x = (const float*)d_in[0];   // [B, N, D] fp32
    const float* W = (const float*)d_in[1];   // [D, D] fp32
    float* out = (float*)d_out;               // [B, P*D] fp32

    BiInteraction_38577396253196_kernel<<<BB / 2, 256, 0, stream>>>(x, W, out);
}